// Round 14
// baseline (799.121 us; speedup 1.0000x reference)
//
#include <hip/hip_runtime.h>

#define B 8
#define L 8
#define E 128
#define NN 1024
#define NODE 256
#define DEP 128
#define FF 384        // NODE + DEP
#define R 40
#define NEDGE (B * L * E)     // 8192
#define GP 8                  // edges per pre-block (same relation)
#define CHUNKS 256            // chunks per relation
#define K4C (NODE / 4)        // 64 float4 steps (ctx part)
#define K4D (DEP / 4)         // 32 float4 steps (dep part)
#define NBLK (B * E)          // 1024 persistent blocks
#define NLEAF 32              // barrier tree leaves (32 blocks each)
#define NPHASE (2 * L)        // 16 barrier phases

// ws layout (floats unless noted):
//   s     [B*NN*DEP]     = 1048576
//   c     [B*NN]         = 8192
//   barL  [NPHASE*32*16] = 8192 (ints)
//   barR  [NPHASE*16]    = 256  (ints)
//   pre   [NEDGE*DEP]    = 1048576
//   cnt   [64]           (ints)
//   bucket[R*NEDGE]      (ints)
//   Wt    [R*K4C*DEP] float4
//   Wd    [R*K4D*DEP] float4
#define ZERO_F4 ((B * NN * DEP + B * NN + NPHASE * NLEAF * 16 + NPHASE * 16) / 4)

// ---------------------------------------------------------------------------
// init: out[b,n,:] = [ctx | 0]; zero s, c, barrier counters; zero cnt.
// ---------------------------------------------------------------------------
__global__ __launch_bounds__(256) void init_kernel(const float4* __restrict__ ctx4,
                                                   float4* __restrict__ out4,
                                                   float4* __restrict__ zero4,
                                                   int* __restrict__ cnt) {
    const float4 z = make_float4(0.f, 0.f, 0.f, 0.f);
    size_t i = (size_t)blockIdx.x * blockDim.x + threadIdx.x;
    size_t stride = (size_t)gridDim.x * blockDim.x;
    const size_t total_out4 = (size_t)B * NN * (FF / 4);
    for (size_t idx = i; idx < total_out4; idx += stride) {
        int f4 = (int)(idx % (FF / 4));
        size_t node = idx / (FF / 4);
        out4[idx] = (f4 < NODE / 4) ? ctx4[node * (NODE / 4) + f4] : z;
    }
    for (size_t idx = i; idx < (size_t)ZERO_F4; idx += stride) zero4[idx] = z;
    if (blockIdx.x == 0 && threadIdx.x < R) cnt[threadIdx.x] = 0;
}

// ---------------------------------------------------------------------------
// pack+bucket fused: k-major repack of W (coalesced matvec reads) and
// relation-bucketing of edges, in one dispatch.
// ---------------------------------------------------------------------------
__global__ __launch_bounds__(256) void pack_bucket_kernel(const float4* __restrict__ W4,
                                                          float4* __restrict__ Wt,
                                                          float4* __restrict__ Wd,
                                                          const int* __restrict__ rels,
                                                          int* __restrict__ cnt,
                                                          int* __restrict__ bucket) {
    int tid = blockIdx.x * 256 + threadIdx.x;
    if (tid < NEDGE) {
        int r = rels[tid];
        int pos = atomicAdd(&cnt[r], 1);
        bucket[r * NEDGE + pos] = tid;
    }
    if (tid < R * (FF / 4) * DEP) {
        int r = tid / ((FF / 4) * DEP);
        int rem = tid % ((FF / 4) * DEP);
        int k4 = rem / DEP;
        int d = rem % DEP;
        float4 v = W4[((size_t)r * DEP + d) * (FF / 4) + k4];
        if (k4 < K4C) Wt[((size_t)r * K4C + k4) * DEP + d] = v;
        else          Wd[((size_t)r * K4D + (k4 - K4C)) * DEP + d] = v;
    }
}

// ---------------------------------------------------------------------------
// pre: pre[gi,d] = (W_ctx[r][d,:] . ctx[b,t,:]) * m  (coalesced Wt reads,
// LDS-broadcast feat, GP same-relation edges per wave). Fully parallel.
// ---------------------------------------------------------------------------
__global__ __launch_bounds__(64) void pre_kernel(const float4* __restrict__ Wt,
                                                 const int* __restrict__ tails,
                                                 const float* __restrict__ mask,
                                                 const float4* __restrict__ ctx4,
                                                 const int* __restrict__ cnt,
                                                 const int* __restrict__ bucket,
                                                 float* __restrict__ pre) {
    int r = blockIdx.x / CHUNKS;
    int chunk = blockIdx.x % CHUNKS;
    int n = cnt[r];
    int start = chunk * GP;
    if (start >= n) return;
    int ng = min(GP, n - start);
    int lane = threadIdx.x;

    __shared__ int gis[GP];
    __shared__ float ms[GP];
    __shared__ float4 feat[GP][K4C];   // 8 KB

    if (lane < ng) {
        int gi = bucket[r * NEDGE + start + lane];
        gis[lane] = gi;
        ms[lane] = mask[gi];
    }
    __syncthreads();
    for (int g = 0; g < ng; ++g) {
        int gi = gis[g];
        int b = gi >> 10;
        int t = tails[gi];
        feat[g][lane] = ctx4[((size_t)b * NN + t) * K4C + lane];
    }
    __syncthreads();

    const float4* wr = Wt + (size_t)r * K4C * DEP;
    float acc0[GP], acc1[GP];
#pragma unroll
    for (int g = 0; g < GP; ++g) { acc0[g] = 0.f; acc1[g] = 0.f; }

    for (int k4 = 0; k4 < K4C; ++k4) {
        float4 w0 = wr[k4 * DEP + lane];
        float4 w1 = wr[k4 * DEP + lane + 64];
#pragma unroll
        for (int g = 0; g < GP; ++g) {
            float4 f = feat[g][k4];
            acc0[g] = fmaf(w0.x, f.x, acc0[g]);
            acc0[g] = fmaf(w0.y, f.y, acc0[g]);
            acc0[g] = fmaf(w0.z, f.z, acc0[g]);
            acc0[g] = fmaf(w0.w, f.w, acc0[g]);
            acc1[g] = fmaf(w1.x, f.x, acc1[g]);
            acc1[g] = fmaf(w1.y, f.y, acc1[g]);
            acc1[g] = fmaf(w1.z, f.z, acc1[g]);
            acc1[g] = fmaf(w1.w, f.w, acc1[g]);
        }
    }
    for (int g = 0; g < ng; ++g) {
        size_t base = (size_t)gis[g] * DEP;
        pre[base + lane]      = acc0[g] * ms[g];
        pre[base + lane + 64] = acc1[g] * ms[g];
    }
}

// ---------------------------------------------------------------------------
// manual grid barrier: phase-indexed tree (32 leaves x 32 blocks -> root).
// Release fence (wbL2) before arrival, acquire fence (invL1/L2) after release
// -> cross-XCD visibility of normal stores; scatters are device-scope atomics.
// Bounded spin: degrades to a wrong answer instead of a GPU hang.
// ---------------------------------------------------------------------------
__device__ __forceinline__ void gridbar(int* __restrict__ barL,
                                        int* __restrict__ barR,
                                        int p, int bid) {
    __syncthreads();
    if (threadIdx.x == 0) {
        __threadfence();                                   // release: wb L2
        int* leaf = barL + ((size_t)p * NLEAF + (bid >> 5)) * 16;
        int old = __hip_atomic_fetch_add(leaf, 1, __ATOMIC_RELAXED,
                                         __HIP_MEMORY_SCOPE_AGENT);
        int* root = barR + (size_t)p * 16;
        if (old == 31)
            __hip_atomic_fetch_add(root, 1, __ATOMIC_RELAXED,
                                   __HIP_MEMORY_SCOPE_AGENT);
        int budget = 1 << 22;
        while (__hip_atomic_load(root, __ATOMIC_RELAXED,
                                 __HIP_MEMORY_SCOPE_AGENT) < NLEAF && --budget)
            __builtin_amdgcn_s_sleep(4);
        __threadfence();                                   // acquire: inv L1/L2
    }
    __syncthreads();
}

// ---------------------------------------------------------------------------
// persistent loop kernel: all 8 layers, 1024 blocks x 128 threads (4/CU).
// Per layer: edge scatter (msg = pre + Wd.child[t], atomicAdd s/c) ->
// gridbar -> node apply (owned 8 nodes: child=s/max(c,1), reset) -> gridbar.
// Layer 0 skips the Wd matvec (child == 0).
// ---------------------------------------------------------------------------
__global__ __launch_bounds__(128) void loop_kernel(const float4* __restrict__ Wd,
                                                   const int* __restrict__ heads,
                                                   const int* __restrict__ tails,
                                                   const int* __restrict__ rels,
                                                   const float* __restrict__ mask,
                                                   float* __restrict__ out,
                                                   const float* __restrict__ pre,
                                                   float* __restrict__ s,
                                                   float* __restrict__ c,
                                                   int* __restrict__ barL,
                                                   int* __restrict__ barR) {
    int be = blockIdx.x;          // b*E + e
    int b = be >> 7;              // E = 128
    int e = be & (E - 1);
    int tid = threadIdx.x;
    int nbase = be * 8;           // owned node range [nbase, nbase+8)

    __shared__ float4 ch[K4D];    // tail child row
    __shared__ float cvs[8];

    for (int k = 0; k < L; ++k) {
        // ---- edge phase ----
        int gi = (b * L + k) * E + e;
        int t = tails[gi], rr = rels[gi];
        int h = heads[gi];
        float m = mask[gi];
        float msg = 0.f;
        bool active = (m != 0.f);

        if (k == 0) {
            if (active) msg = pre[(size_t)gi * DEP + tid];
        } else {
            if (tid < K4D)
                ch[tid] = ((const float4*)(out + ((size_t)b * NN + t) * FF + NODE))[tid];
            __syncthreads();
            if (active) {
                const float4* wr = Wd + (size_t)rr * K4D * DEP;
                float accA = 0.f, accB = 0.f;
#pragma unroll
                for (int k4 = 0; k4 < K4D; k4 += 2) {
                    float4 w0 = wr[k4 * DEP + tid];
                    float4 f0 = ch[k4];
                    accA = fmaf(w0.x, f0.x, accA);
                    accA = fmaf(w0.y, f0.y, accA);
                    accA = fmaf(w0.z, f0.z, accA);
                    accA = fmaf(w0.w, f0.w, accA);
                    float4 w1 = wr[(k4 + 1) * DEP + tid];
                    float4 f1 = ch[k4 + 1];
                    accB = fmaf(w1.x, f1.x, accB);
                    accB = fmaf(w1.y, f1.y, accB);
                    accB = fmaf(w1.z, f1.z, accB);
                    accB = fmaf(w1.w, f1.w, accB);
                }
                msg = pre[(size_t)gi * DEP + tid] + (accA + accB) * m;
            }
            __syncthreads();   // protect ch before next reuse
        }
        if (active) {
            atomicAdd(&s[((size_t)b * NN + h) * DEP + tid], msg);
            if (tid == 0) atomicAdd(&c[(size_t)b * NN + h], m);
        }
        gridbar(barL, barR, 2 * k, be);

        // ---- node phase: owned 8 nodes ----
        if (tid < 8) cvs[tid] = c[nbase + tid];
        __syncthreads();
#pragma unroll
        for (int kk = 0; kk < 8; ++kk) {
            float cv = cvs[kk];
            if (cv > 0.f) {
                int node = nbase + kk;
                size_t si = (size_t)node * DEP + tid;
                out[(size_t)node * FF + NODE + tid] = s[si] / fmaxf(cv, 1.f);
                s[si] = 0.f;
            }
        }
        if (tid < 8 && cvs[tid] > 0.f) c[nbase + tid] = 0.f;
        gridbar(barL, barR, 2 * k + 1, be);
    }
}

extern "C" void kernel_launch(void* const* d_in, const int* in_sizes, int n_in,
                              void* d_out, int out_size, void* d_ws, size_t ws_size,
                              hipStream_t stream) {
    const float* ctx  = (const float*)d_in[0];   // [B,N,NODE]
    const float* W    = (const float*)d_in[1];   // [R,DEP,F]
    const int* heads  = (const int*)d_in[2];     // [B,L,E]
    const int* tails  = (const int*)d_in[3];
    const int* rels   = (const int*)d_in[4];
    const float* mask = (const float*)d_in[5];

    float* out = (float*)d_out;                       // [B,N,F]

    float* s    = (float*)d_ws;                       // [B,N,DEP]
    float* c    = s + (size_t)B * NN * DEP;           // [B,N]
    int*   barL = (int*)(c + (size_t)B * NN);         // [NPHASE*32*16]
    int*   barR = barL + NPHASE * NLEAF * 16;         // [NPHASE*16]
    float* pre  = (float*)(barR + NPHASE * 16);       // [B,L,E,DEP]
    int*   cnt  = (int*)(pre + (size_t)NEDGE * DEP);  // [64]
    int* bucket = cnt + 64;                           // [R,NEDGE]
    float4* Wt  = (float4*)(bucket + R * NEDGE);      // [R,K4C,DEP]
    float4* Wd  = Wt + (size_t)R * K4C * DEP;         // [R,K4D,DEP]

    init_kernel<<<2048, 256, 0, stream>>>((const float4*)ctx, (float4*)out,
                                          (float4*)d_ws, cnt);
    pack_bucket_kernel<<<(R * (FF / 4) * DEP + 255) / 256, 256, 0, stream>>>(
        (const float4*)W, Wt, Wd, rels, cnt, bucket);
    pre_kernel<<<R * CHUNKS, 64, 0, stream>>>(Wt, tails, mask,
                                              (const float4*)ctx, cnt, bucket, pre);
    loop_kernel<<<NBLK, 128, 0, stream>>>(Wd, heads, tails, rels, mask,
                                          out, pre, s, c, barL, barR);
}